// Round 1
// 272.589 us; speedup vs baseline: 1.0753x; 1.0753x over previous
//
#include <hip/hip_runtime.h>
#include <stdint.h>
#include <math.h>

#define D 128

typedef unsigned short u16;
typedef __attribute__((ext_vector_type(8))) short bf16x8;
typedef __attribute__((ext_vector_type(4))) float f32x4;
typedef __attribute__((ext_vector_type(2))) float f32x2;

union BU { uint4 u; bf16x8 s; };

// bf16 pack/unpack (RNE)
__device__ __forceinline__ unsigned f2bf_pk(float a, float b) {
    union { float f; unsigned u; } x, y; x.f = a; y.f = b;
    unsigned ra = x.u + 0x7FFF + ((x.u >> 16) & 1);
    unsigned rb = y.u + 0x7FFF + ((y.u >> 16) & 1);
    return (ra >> 16) | (rb & 0xFFFF0000u);
}
__device__ __forceinline__ u16 f2bf(float f) {
    union { float f; unsigned u; } x; x.f = f;
    unsigned r = x.u + 0x7FFF + ((x.u >> 16) & 1);
    return (u16)(r >> 16);
}
__device__ __forceinline__ f32x2 bf2f2v(unsigned u) {
    union { unsigned w[2]; f32x2 v; } t;
    t.w[0] = u << 16; t.w[1] = u & 0xFFFF0000u;
    return t.v;
}
__device__ __forceinline__ f32x2 vmax0(f32x2 a) {
    return __builtin_elementwise_max(a, (f32x2)(0.f));
}
// pad to batch granularity 4 (0 allowed for isolated nodes)
__device__ __forceinline__ int padded4(int deg) {
    return (deg + 3) & ~3;
}

// ---- CSR build: 8-way privatized histogram, int4-vectorized ----
// Also records each edge's within-(copy,node) rank (the atomicAdd return),
// so the later scatter needs NO atomics (pure load -> store).

__global__ __launch_bounds__(256) void k_degree8(const int* __restrict__ dst, int E,
                                                 int* __restrict__ hist8, int* __restrict__ rank, int N) {
    int i = blockIdx.x * 256 + threadIdx.x;
    int copy = blockIdx.x & 7;
    int E4 = E >> 2;
    if (i < E4) {
        int4 d = ((const int4*)dst)[i];
        int* h = hist8 + copy * N;
        int4 rk;
        rk.x = atomicAdd(&h[d.x], 1);
        rk.y = atomicAdd(&h[d.y], 1);
        rk.z = atomicAdd(&h[d.z], 1);
        rk.w = atomicAdd(&h[d.w], 1);
        ((int4*)rank)[i] = rk;
    }
    if (i == 0) {
        for (int j = E4 * 4; j < E; ++j) rank[j] = atomicAdd(&hist8[dst[j]], 1);   // copy 0
    }
}

__global__ __launch_bounds__(256) void k_xcdoff_bsum(int* __restrict__ hist8, int* __restrict__ degi,
                                                     float* __restrict__ dinv, int* __restrict__ bsum, int N) {
    __shared__ int ws[4];
    int t = threadIdx.x;
    int i = blockIdx.x * 256 + t;
    int pd = 0;
    if (i < N) {
        int run = 0;
#pragma unroll
        for (int j = 0; j < 8; ++j) {
            int c = hist8[j * N + i];
            hist8[j * N + i] = run;
            run += c;
        }
        degi[i] = run;
        dinv[i] = rsqrtf((float)run + 1.0f);
        pd = padded4(run);
    }
    int v = pd;
#pragma unroll
    for (int off = 1; off < 64; off <<= 1) v += __shfl_xor(v, off, 64);
    if ((t & 63) == 0) ws[t >> 6] = v;
    __syncthreads();
    if (t == 0) bsum[blockIdx.x] = ws[0] + ws[1] + ws[2] + ws[3];
}

__global__ __launch_bounds__(1024) void k_boff_wprep(const int* __restrict__ bsum, int* __restrict__ boff,
                                                     int nb, int* __restrict__ prow, int N,
                                                     const float* __restrict__ W2, const float* __restrict__ Wlin,
                                                     unsigned* __restrict__ wswz) {
    int t = threadIdx.x;
    if (blockIdx.x == 0) {
        __shared__ int s[1024];
        s[t] = (t < nb) ? bsum[t] : 0;
        __syncthreads();
        for (int off = 1; off < 1024; off <<= 1) {
            int v = (t >= off) ? s[t - off] : 0;
            __syncthreads();
            s[t] += v;
            __syncthreads();
        }
        if (t < nb) boff[t] = (t == 0) ? 0 : s[t - 1];
        if (t == 0) prow[N] = s[1023];
    } else {
        int tid = (blockIdx.x - 1) * 1024 + t;       // 0..24575 = 3*8192
        int m = tid >> 13;
        int r = tid & 8191;
        int jp = r & 3;
        int lane = (r >> 2) & 63;
        int ct = (r >> 8) & 7;
        int kc = r >> 11;
        int k0 = kc * 32 + (lane >> 4) * 8 + 2 * jp;
        int n = ct * 16 + (lane & 15);
        const float* srcp = (m == 0) ? W2 : (Wlin + (m - 1) * 16384);
        wswz[tid] = f2bf_pk(srcp[k0 * 128 + n], srcp[(k0 + 1) * 128 + n]);
    }
}

// Final scan; also folds prow into the 8 per-copy hist8 bases so the scatter
// kernel's position is a single load: pos = hist8[copy*N+d] + rank[e].
__global__ __launch_bounds__(256) void k_scan_final(const int* __restrict__ degi, const int* __restrict__ boff,
                                                    int* __restrict__ prow, int N, int* __restrict__ hist8) {
    __shared__ int s[256];
    int t = threadIdx.x;
    int i = blockIdx.x * 256 + t;
    int pd = (i < N) ? padded4(degi[i]) : 0;
    s[t] = pd;
    __syncthreads();
    for (int off = 1; off < 256; off <<= 1) {
        int v = (t >= off) ? s[t - off] : 0;
        __syncthreads();
        s[t] += v;
        __syncthreads();
    }
    if (i < N) {
        int p = boff[blockIdx.x] + ((t == 0) ? 0 : s[t - 1]);
        prow[i] = p;
#pragma unroll
        for (int j = 0; j < 8; ++j) hist8[j * N + i] += p;
    }
}

// ---- Merged dispatch: atomic-free scatter (int payload) | pad fill | xform1 ----
// blocks [0, eb4)           : scatter src ids into padded CSR (no atomics, no eid)
// blocks [eb4, eb4+nb)      : fill pad slots with N; block eb4 also fills tail sentinels
// blocks [eb4+nb, ...+xb)   : g1 = bf16(dinv * (x @ W1)) (+ zero sentinel row)

__global__ __launch_bounds__(256) void k_scatter_fill_xform(
        const int* __restrict__ src, const int* __restrict__ dst, int E,
        const int* __restrict__ prow, const int* __restrict__ hist8, const int* __restrict__ rank,
        const int* __restrict__ degi,
        int* __restrict__ colsrc, int N, int eb4, int nb,
        const float* __restrict__ x, const float* __restrict__ W1,
        const float* __restrict__ dinv, unsigned* __restrict__ g) {
    __shared__ float Ws[8 * D];
    int t = threadIdx.x;
    int b = blockIdx.x;
    if (b < eb4) {
        int i = b * 256 + t;
        int copy = b & 7;
        int E4 = E >> 2;
        if (i < E4) {
            int4 d = ((const int4*)dst)[i];
            int4 s4 = ((const int4*)src)[i];
            int4 rk = ((const int4*)rank)[i];
            const int* h = hist8 + copy * N;
            colsrc[h[d.x] + rk.x] = s4.x;
            colsrc[h[d.y] + rk.y] = s4.y;
            colsrc[h[d.z] + rk.z] = s4.z;
            colsrc[h[d.w] + rk.w] = s4.w;
        }
        if (i == 0) {
            for (int j = E4 * 4; j < E; ++j)
                colsrc[hist8[dst[j]] + rank[j]] = src[j];   // copy 0
        }
    } else if (b < eb4 + nb) {
        int n = (b - eb4) * 256 + t;
        if (n < N) {
            int lo = prow[n];
            int deg = degi[n];
            int pd = padded4(deg);
            for (int j = deg; j < pd; ++j) colsrc[lo + j] = N;
        }
        if (b == eb4 && t == 0) {
            int P = prow[N];
            for (int j = 0; j < 16; ++j) colsrc[P + j] = N;
        }
    } else {
        int xb0 = b - eb4 - nb;
        for (int i = t; i < 8 * D; i += 256) Ws[i] = W1[i];
        __syncthreads();
        int node = xb0 * 4 + (t >> 6);
        int l = t & 63;
        if (node < N) {
            float s0 = 0.f, s1 = 0.f;
#pragma unroll
            for (int k = 0; k < 8; ++k) {
                float xv = x[node * 8 + k];
                s0 += xv * Ws[k * D + 2 * l];
                s1 += xv * Ws[k * D + 2 * l + 1];
            }
            float di = dinv[node];
            g[node * 64 + l] = f2bf_pk(s0 * di, s1 * di);
        }
        if (xb0 == 0 && t < 64) g[(size_t)N * 64 + t] = 0;   // zero sentinel row
    }
}

// ---- Fused aggregation + MFMA GEMM ----
// Block = 4 waves, 16-node tile. Each wave aggregates 4 nodes (CSR gather, packed f32x2 math),
// stages h rows (bf16) in LDS; then each wave MFMAs the tile against 2 column-tiles of W.
// DUAL=false: out0 = bf16(dinv * (h@W0))            (layer-2 g2)
// DUAL=true : out0 = bf16(h@W0) ; out1 = bf16(h@W1 + bias1)   (edge-MLP a,c)

#define HROW 136   // u16 per LDS row (128 + 8 pad -> 272 B row stride)

template <bool DUAL>
__global__ __launch_bounds__(256) void k_aggemm(const uint4* __restrict__ g, const int* __restrict__ prow,
                                                const int* __restrict__ colsrc, const float* __restrict__ dinv,
                                                const float* __restrict__ biasH,
                                                const uint4* __restrict__ wB0, const uint4* __restrict__ wB1,
                                                const float* __restrict__ bias1,
                                                u16* __restrict__ out0, u16* __restrict__ out1, int N) {
    __shared__ u16 hs[16 * HROW];
    int t = threadIdx.x;
    int wv = t >> 6;
    int lane = t & 63;
    int sub = lane >> 4;
    int r = lane & 15;
    int base = blockIdx.x * 16;

    // ---- aggregation phase: 4 nodes per wave ----
    for (int nd = 0; nd < 4; ++nd) {
        int i = base + wv * 4 + nd;
        int lrow = wv * 4 + nd;
        if (i < N) {
            f32x2 acc2[4];
#pragma unroll
            for (int j = 0; j < 4; ++j) acc2[j] = (f32x2)(0.f);
            int lo = prow[i], hiP = prow[i + 1];
            int idx = lo + sub;
            int c0 = colsrc[idx];
            int c1 = (idx + 4 < hiP) ? colsrc[idx + 4] : N;
            int c2 = (idx + 8 < hiP) ? colsrc[idx + 8] : N;
            uint4 v0 = g[c0 * 16 + r];
            uint4 v1 = g[c1 * 16 + r];
            for (int k = lo; k < hiP; k += 4) {
                int c3 = (idx + 12 < hiP) ? colsrc[idx + 12] : N;
                uint4 v2 = g[c2 * 16 + r];
                acc2[0] += bf2f2v(v0.x);
                acc2[1] += bf2f2v(v0.y);
                acc2[2] += bf2f2v(v0.z);
                acc2[3] += bf2f2v(v0.w);
                v0 = v1; v1 = v2; c2 = c3; idx += 4;
            }
#pragma unroll
            for (int j = 0; j < 4; ++j) {
                acc2[j].x += __shfl_xor(acc2[j].x, 16, 64);
                acc2[j].y += __shfl_xor(acc2[j].y, 16, 64);
                acc2[j].x += __shfl_xor(acc2[j].x, 32, 64);
                acc2[j].y += __shfl_xor(acc2[j].y, 32, 64);
            }
            if (sub == 0) {
                uint4 sv = g[i * 16 + r];   // self term
                acc2[0] += bf2f2v(sv.x);
                acc2[1] += bf2f2v(sv.y);
                acc2[2] += bf2f2v(sv.z);
                acc2[3] += bf2f2v(sv.w);
                float di = dinv[i];
                float4 b0 = ((const float4*)biasH)[r * 2];
                float4 b1v = ((const float4*)biasH)[r * 2 + 1];
                float r0 = fmaxf(acc2[0].x * di + b0.x, 0.f);
                float r1 = fmaxf(acc2[0].y * di + b0.y, 0.f);
                float r2 = fmaxf(acc2[1].x * di + b0.z, 0.f);
                float r3 = fmaxf(acc2[1].y * di + b0.w, 0.f);
                float r4 = fmaxf(acc2[2].x * di + b1v.x, 0.f);
                float r5 = fmaxf(acc2[2].y * di + b1v.y, 0.f);
                float r6 = fmaxf(acc2[3].x * di + b1v.z, 0.f);
                float r7 = fmaxf(acc2[3].y * di + b1v.w, 0.f);
                uint4 o;
                o.x = f2bf_pk(r0, r1);
                o.y = f2bf_pk(r2, r3);
                o.z = f2bf_pk(r4, r5);
                o.w = f2bf_pk(r6, r7);
                *(uint4*)(hs + lrow * HROW + r * 8) = o;
            }
        } else if (sub == 0) {
            *(uint4*)(hs + lrow * HROW + r * 8) = make_uint4(0, 0, 0, 0);
        }
    }
    __syncthreads();

    // ---- GEMM phase: wave wv handles column-tiles ct0, ct0+1 ----
    int quad = lane >> 4;
    int l15 = lane & 15;
    int ct0 = wv * 2;

    f32x4 accA[2], accB[2];
#pragma unroll
    for (int q = 0; q < 2; ++q) { accA[q] = (f32x4){0.f, 0.f, 0.f, 0.f}; accB[q] = (f32x4){0.f, 0.f, 0.f, 0.f}; }

    const uint4* hrow = (const uint4*)(hs + l15 * HROW);
#pragma unroll
    for (int kc = 0; kc < 4; ++kc) {
        BU a; a.u = hrow[kc * 4 + quad];
#pragma unroll
        for (int q = 0; q < 2; ++q) {
            BU b0; b0.u = wB0[(kc * 8 + ct0 + q) * 64 + lane];
            accA[q] = __builtin_amdgcn_mfma_f32_16x16x32_bf16(a.s, b0.s, accA[q], 0, 0, 0);
            if (DUAL) {
                BU b1; b1.u = wB1[(kc * 8 + ct0 + q) * 64 + lane];
                accB[q] = __builtin_amdgcn_mfma_f32_16x16x32_bf16(a.s, b1.s, accB[q], 0, 0, 0);
            }
        }
    }
#pragma unroll
    for (int reg = 0; reg < 4; ++reg) {
        int node = base + quad * 4 + reg;
        if (node >= N) continue;
        float sc = DUAL ? 1.0f : dinv[node];
#pragma unroll
        for (int q = 0; q < 2; ++q) {
            int colj = (ct0 + q) * 16 + l15;
            out0[(size_t)node * 128 + colj] = f2bf(accA[q][reg] * sc);
            if (DUAL) out1[(size_t)node * 128 + colj] = f2bf(accB[q][reg] + bias1[colj]);
        }
    }
    if (blockIdx.x == 0 && t < 64) ((unsigned*)out0)[(size_t)N * 64 + t] = 0;   // zero sentinel row
}

// ---- Edge output: ORIGINAL edge order ----
// 16 lanes per edge, 2 edges per group for ILP. Reads a[src], c[dst] rows
// (random, L2/LLC-resident); writes out coalesced (no eid scatter).

__global__ __launch_bounds__(256) void k_edge(const uint4* __restrict__ a, const uint4* __restrict__ c,
                                              const int* __restrict__ src, const int* __restrict__ dst,
                                              const float* __restrict__ Wfin, const float* __restrict__ bfin,
                                              float* __restrict__ out, int E) {
    int t = threadIdx.x;
    int g = t >> 4;
    int r = t & 15;
    int base = blockIdx.x * 32;
    int e0 = base + g;
    int e1 = base + 16 + g;
    bool ok0 = e0 < E, ok1 = e1 < E;
    int ec0 = ok0 ? e0 : 0;
    int ec1 = ok1 ? e1 : 0;

    int s0 = src[ec0], d0 = dst[ec0];
    int s1 = src[ec1], d1 = dst[ec1];
    uint4 av0 = a[(size_t)s0 * 16 + r];
    uint4 cv0 = c[(size_t)d0 * 16 + r];
    uint4 av1 = a[(size_t)s1 * 16 + r];
    uint4 cv1 = c[(size_t)d1 * 16 + r];

    f32x2 wf0v[4], wf1v[4];
    const float4* wvp = (const float4*)Wfin;
#pragma unroll
    for (int q = 0; q < 4; ++q) {
        float4 m = wvp[r * 4 + q];
        wf0v[q] = (f32x2){m.x, m.z};
        wf1v[q] = (f32x2){m.y, m.w};
    }
    float bf0 = bfin[0], bf1 = bfin[1];

    f32x2 p0a = (f32x2)(0.f), p1a = (f32x2)(0.f);
    f32x2 p0b = (f32x2)(0.f), p1b = (f32x2)(0.f);
    f32x2 z;
    z = vmax0(bf2f2v(av0.x) + bf2f2v(cv0.x)); p0a += z * wf0v[0]; p1a += z * wf1v[0];
    z = vmax0(bf2f2v(av0.y) + bf2f2v(cv0.y)); p0a += z * wf0v[1]; p1a += z * wf1v[1];
    z = vmax0(bf2f2v(av0.z) + bf2f2v(cv0.z)); p0a += z * wf0v[2]; p1a += z * wf1v[2];
    z = vmax0(bf2f2v(av0.w) + bf2f2v(cv0.w)); p0a += z * wf0v[3]; p1a += z * wf1v[3];
    z = vmax0(bf2f2v(av1.x) + bf2f2v(cv1.x)); p0b += z * wf0v[0]; p1b += z * wf1v[0];
    z = vmax0(bf2f2v(av1.y) + bf2f2v(cv1.y)); p0b += z * wf0v[1]; p1b += z * wf1v[1];
    z = vmax0(bf2f2v(av1.z) + bf2f2v(cv1.z)); p0b += z * wf0v[2]; p1b += z * wf1v[2];
    z = vmax0(bf2f2v(av1.w) + bf2f2v(cv1.w)); p0b += z * wf0v[3]; p1b += z * wf1v[3];

    float q0 = p0a.x + p0a.y, q1 = p1a.x + p1a.y;
    float q2 = p0b.x + p0b.y, q3 = p1b.x + p1b.y;
#pragma unroll
    for (int off = 1; off < 16; off <<= 1) {
        q0 += __shfl_xor(q0, off, 64);
        q1 += __shfl_xor(q1, off, 64);
        q2 += __shfl_xor(q2, off, 64);
        q3 += __shfl_xor(q3, off, 64);
    }
    if (r == 0) {
        if (ok0) {
            float l0 = q0 + bf0, l1 = q1 + bf1;
            float m = fmaxf(l0, l1);
            float lse = m + __logf(__expf(l0 - m) + __expf(l1 - m));
            *((float2*)(out + 2 * (size_t)e0)) = make_float2(l0 - lse, l1 - lse);
        }
        if (ok1) {
            float l0 = q2 + bf0, l1 = q3 + bf1;
            float m = fmaxf(l0, l1);
            float lse = m + __logf(__expf(l0 - m) + __expf(l1 - m));
            *((float2*)(out + 2 * (size_t)e1)) = make_float2(l0 - lse, l1 - lse);
        }
    }
}

extern "C" void kernel_launch(void* const* d_in, const int* in_sizes, int n_in,
                              void* d_out, int out_size, void* d_ws, size_t ws_size,
                              hipStream_t stream) {
    const float* x     = (const float*)d_in[0];
    const int*   ei    = (const int*)d_in[1];
    const float* W1    = (const float*)d_in[2];
    const float* b1    = (const float*)d_in[3];
    const float* W2    = (const float*)d_in[4];
    const float* b2    = (const float*)d_in[5];
    const float* Wlin1 = (const float*)d_in[6];
    const float* blin1 = (const float*)d_in[7];
    const float* Wfin  = (const float*)d_in[8];
    const float* bfin  = (const float*)d_in[9];
    float* out = (float*)d_out;

    int N = in_sizes[0] / 8;
    int E = in_sizes[1] / 2;
    const int* src = ei;
    const int* dst = ei + E;
    int nb = (N + 255) / 256;
    int eb4 = (E / 4 + 255) / 256;
    int xb = (N + 3) / 4;

    char* w = (char*)d_ws;
    int* hist8 = (int*)w;     w += (size_t)8 * N * 4;
    int* rank = (int*)w;      w += (size_t)E * 4;
    int* degi = (int*)w;      w += (size_t)N * 4;
    int* prow = (int*)w;      w += (size_t)(N + 1) * 4;
    float* dinv = (float*)w;  w += (size_t)N * 4;
    int* bsum = (int*)w;      w += (size_t)nb * 4;
    int* boff = (int*)w;      w += (size_t)nb * 4;
    w = (char*)(((uintptr_t)w + 255) & ~(uintptr_t)255);
    int* colsrc = (int*)w;    w += ((size_t)E + 8 * (size_t)N + 64) * 4;
    unsigned* wswz = (unsigned*)w; w += (size_t)3 * 8192 * 4;
    unsigned* bufG = (unsigned*)w; w += (size_t)(N + 1) * 64 * 4;   // g1 + sentinel
    unsigned* bufA = (unsigned*)w; w += (size_t)(N + 1) * 64 * 4;   // a + sentinel
    unsigned* bufC = (unsigned*)w; w += (size_t)N * 64 * 4;         // c
    unsigned* bufG2 = (unsigned*)w; w += (size_t)(N + 1) * 64 * 4;  // g2 + sentinel

    hipMemsetAsync(hist8, 0, (size_t)8 * N * 4, stream);

    k_degree8<<<eb4, 256, 0, stream>>>(dst, E, hist8, rank, N);
    k_xcdoff_bsum<<<nb, 256, 0, stream>>>(hist8, degi, dinv, bsum, N);
    k_boff_wprep<<<25, 1024, 0, stream>>>(bsum, boff, nb, prow, N, W2, Wlin1, wswz);
    k_scan_final<<<nb, 256, 0, stream>>>(degi, boff, prow, N, hist8);
    // merged: atomic-free scatter | pad fill | layer-1 transform (independent work, one dispatch)
    k_scatter_fill_xform<<<eb4 + nb + xb, 256, 0, stream>>>(src, dst, E, prow, hist8, rank, degi,
                                                            colsrc, N, eb4, nb, x, W1, dinv, bufG);

    int ablocks = (N + 15) / 16;
    // fused: agg(g1)->h1 -> GEMM W2 -> g2 (dinv-scaled) + sentinel
    k_aggemm<false><<<ablocks, 256, 0, stream>>>((const uint4*)bufG, prow, colsrc, dinv, b1,
                                                 (const uint4*)wswz, nullptr, nullptr,
                                                 (u16*)bufG2, nullptr, N);
    // fused: agg(g2)->h2 -> dual GEMM -> a (+sentinel), c (+blin1)
    k_aggemm<true><<<ablocks, 256, 0, stream>>>((const uint4*)bufG2, prow, colsrc, dinv, b2,
                                                (const uint4*)(wswz + 8192), (const uint4*)(wswz + 16384),
                                                blin1, (u16*)bufA, (u16*)bufC, N);

    k_edge<<<(E + 31) / 32, 256, 0, stream>>>((const uint4*)bufA, (const uint4*)bufC,
                                              src, dst, Wfin, bfin, out, E);
}